// Round 1
// baseline (1098.977 us; speedup 1.0000x reference)
//
#include <hip/hip_runtime.h>
#include <math.h>

// Problem constants
#define BATCH   8
#define S_LEN   1024
#define D_MODEL 1280
#define DX      768
#define NH      8
#define HD      160
#define LTXT    77
#define NBH     (BATCH*NH)      // 64
#define HDIM16  2560            // 16*HD

// ---------------------------------------------------------------------------
// Generic fp32 tiled GEMM: C[M,N] = A[M,K] @ B[K,N] (+ bias)
// 64x64 tile, 256 threads, 4x4 per thread, BK=16. K%16==0, N%64==0 assumed.
// ---------------------------------------------------------------------------
__global__ __launch_bounds__(256) void gemm_f32(
    const float* __restrict__ A, const float* __restrict__ B,
    float* __restrict__ C, int M, int K, int N,
    const float* __restrict__ bias)
{
    __shared__ float As[16][68];   // [k][m], padded stride 68 (2-way max)
    __shared__ float Bs[16][68];   // [k][n]
    const int t  = threadIdx.x;
    const int tx = t & 15, ty = t >> 4;
    const int m0 = blockIdx.y * 64, n0 = blockIdx.x * 64;
    const int arow = t >> 2, akk = (t & 3) * 4;   // A tile: 64 rows x 16 k
    const int brow = t >> 4, bcol = (t & 15) * 4; // B tile: 16 k x 64 cols

    float acc[4][4] = {};

    for (int k0 = 0; k0 < K; k0 += 16) {
        float4 av = make_float4(0.f, 0.f, 0.f, 0.f);
        if (m0 + arow < M)
            av = *(const float4*)&A[(size_t)(m0 + arow) * K + k0 + akk];
        As[akk + 0][arow] = av.x;
        As[akk + 1][arow] = av.y;
        As[akk + 2][arow] = av.z;
        As[akk + 3][arow] = av.w;
        *(float4*)&Bs[brow][bcol] =
            *(const float4*)&B[(size_t)(k0 + brow) * N + n0 + bcol];
        __syncthreads();
#pragma unroll
        for (int kk = 0; kk < 16; ++kk) {
            float a_[4], b_[4];
#pragma unroll
            for (int i = 0; i < 4; ++i) a_[i] = As[kk][ty * 4 + i];
#pragma unroll
            for (int j = 0; j < 4; ++j) b_[j] = Bs[kk][tx * 4 + j];
#pragma unroll
            for (int i = 0; i < 4; ++i)
#pragma unroll
                for (int j = 0; j < 4; ++j) acc[i][j] += a_[i] * b_[j];
        }
        __syncthreads();
    }

#pragma unroll
    for (int i = 0; i < 4; ++i) {
        int row = m0 + ty * 4 + i;
        if (row < M) {
#pragma unroll
            for (int j = 0; j < 4; ++j) {
                int col = n0 + tx * 4 + j;
                float v = acc[i][j];
                if (bias) v += bias[col];
                C[(size_t)row * N + col] = v;
            }
        }
    }
}

// ---------------------------------------------------------------------------
// Ortho-decomp retain transform, applied in place to vbuf [8][77][1280].
// One block per (r, l), r in [0,4), l in [0,77). 256 threads.
//   era[d] = sum_e coef[e]*T[l,e,d],  coef[e] = cos_g[e] * sum_c w[c]*Pm[c,e]
// Only needs: G = T.T^T (3x3), tp = T.pro (3), pp = |pro|^2.
// ---------------------------------------------------------------------------
__global__ __launch_bounds__(256) void retain_kernel(
    float* __restrict__ vbuf, const float* __restrict__ tv)
{
    const int l = blockIdx.x % LTXT;
    const int r = blockIdx.x / LTXT;
    const int t = threadIdx.x;

    // Partial sums over the 2560-long concatenated vectors
    float g00=0,g01=0,g02=0,g11=0,g12=0,g22=0,tp0=0,tp1=0,tp2=0,pp=0;
    float p_save[10];
#pragma unroll
    for (int it = 0; it < 10; ++it) {
        const int j   = t + it * 256;          // 0..2559
        const int m16 = j / HD, d = j % HD;    // 16-map index, head-dim
        const int e = m16 >> 3, h = m16 & 7;
        const float T0 = tv[((size_t)(e*24 +  0 + h) * LTXT + l) * HD + d];
        const float T1 = tv[((size_t)(e*24 +  8 + h) * LTXT + l) * HD + d];
        const float T2 = tv[((size_t)(e*24 + 16 + h) * LTXT + l) * HD + d];
        const float p  = vbuf[((size_t)((e*4 + r) * LTXT + l)) * D_MODEL + h*HD + d];
        p_save[it] = p;
        g00 += T0*T0; g01 += T0*T1; g02 += T0*T2;
        g11 += T1*T1; g12 += T1*T2; g22 += T2*T2;
        tp0 += T0*p;  tp1 += T1*p;  tp2 += T2*p;  pp += p*p;
    }

    // Deterministic block reduction: wave shuffle -> per-wave partials -> sum
    __shared__ float part[4][10];
    const int wave = t >> 6, lane = t & 63;
    float vals[10] = {g00,g01,g02,g11,g12,g22,tp0,tp1,tp2,pp};
#pragma unroll
    for (int i = 0; i < 10; ++i) {
        float x = vals[i];
        x += __shfl_down(x, 32); x += __shfl_down(x, 16);
        x += __shfl_down(x,  8); x += __shfl_down(x,  4);
        x += __shfl_down(x,  2); x += __shfl_down(x,  1);
        if (lane == 0) part[wave][i] = x;
    }
    __syncthreads();

    float s[10];
#pragma unroll
    for (int i = 0; i < 10; ++i)
        s[i] = part[0][i] + part[1][i] + part[2][i] + part[3][i];

    const float G[3][3] = {{s[0],s[1],s[2]},{s[1],s[3],s[4]},{s[2],s[4],s[5]}};
    const float tp[3] = {s[6], s[7], s[8]};
    const float ppv = s[9];

    // Pm = I - strict_lower(G[c][e] / G[e][e])
    float Pm[3][3];
#pragma unroll
    for (int c = 0; c < 3; ++c)
#pragma unroll
        for (int e = 0; e < 3; ++e) {
            float v = (c == e) ? 1.f : 0.f;
            if (c > e) v -= G[c][e] / G[e][e];
            Pm[c][e] = v;
        }

    const float nP = fmaxf(sqrtf(ppv), 1e-8f);
    float w[3], cosg[3];
#pragma unroll
    for (int c = 0; c < 3; ++c) {
        const float nT = fmaxf(sqrtf(G[c][c]), 1e-8f);
        const float cosv = tp[c] / (nT * nP);
        cosg[c] = 1.f / (1.f + expf(-10.f * (cosv - 0.5f)));
        float d1 = Pm[c][0]*tp[0] + Pm[c][1]*tp[1] + Pm[c][2]*tp[2];
        float d2 = 0.f;
#pragma unroll
        for (int e = 0; e < 3; ++e)
#pragma unroll
            for (int f = 0; f < 3; ++f) d2 += Pm[c][e] * Pm[c][f] * G[e][f];
        float wc = d1 / d2;
        if (isnan(wc)) wc = 0.f;                 // nan_to_num
        if (l == 0)    wc = 0.f;                 // weight[:,0,:] = 0 (BOS)
        w[c] = wc;
    }

    float coef[3];
#pragma unroll
    for (int e = 0; e < 3; ++e)
        coef[e] = cosg[e] * (w[0]*Pm[0][e] + w[1]*Pm[1][e] + w[2]*Pm[2][e]);

    // ret = pro - sum_e coef[e]*T[e], written back in place
#pragma unroll
    for (int it = 0; it < 10; ++it) {
        const int j   = t + it * 256;
        const int m16 = j / HD, d = j % HD;
        const int e = m16 >> 3, h = m16 & 7;
        const float T0 = tv[((size_t)(e*24 +  0 + h) * LTXT + l) * HD + d];
        const float T1 = tv[((size_t)(e*24 +  8 + h) * LTXT + l) * HD + d];
        const float T2 = tv[((size_t)(e*24 + 16 + h) * LTXT + l) * HD + d];
        const float era = coef[0]*T0 + coef[1]*T1 + coef[2]*T2;
        vbuf[((size_t)((e*4 + r) * LTXT + l)) * D_MODEL + h*HD + d] = p_save[it] - era;
    }
}

// ---------------------------------------------------------------------------
// Attention: per block = one (b,h) pair x 16 queries.
//   scores = softmax(q.k^T / sqrt(160)); hs = scores @ v
// K and V staged TRANSPOSED in LDS [160][78] so both hot loops read
// (near-)conflict-free. hs written in place over q (same region each block).
// ---------------------------------------------------------------------------
__global__ __launch_bounds__(256) void attn_kernel(
    const float* __restrict__ kbuf, const float* __restrict__ vbuf,
    float* __restrict__ qhs)
{
    __shared__ float qs[16][HD];     // 10,240 B
    __shared__ float kT[HD][78];     // 49,920 B (transposed K, then V)
    __shared__ float sc[16][78];     //  4,992 B   -> total 65,152 B
    const int bh = blockIdx.x;
    const int b = bh >> 3, h = bh & 7;
    const int q0 = blockIdx.y * 16;
    const int t = threadIdx.x;

    // Load q tile: 16 x 160 = 640 float4
    float* qbase = qhs + ((size_t)(b * S_LEN + q0)) * D_MODEL + h * HD;
    for (int idx = t; idx < 640; idx += 256) {
        const int qi = idx / 40, d4 = idx % 40;
        *(float4*)&qs[qi][d4 * 4] = *(const float4*)&qbase[(size_t)qi * D_MODEL + d4 * 4];
    }
    // Load K transposed: 77 x 160 = 3080 float4
    const float* kbase = kbuf + ((size_t)(b * LTXT)) * D_MODEL + h * HD;
    for (int idx = t; idx < 3080; idx += 256) {
        const int l = idx / 40, d4 = idx % 40;
        const float4 v = *(const float4*)&kbase[(size_t)l * D_MODEL + d4 * 4];
        kT[d4*4 + 0][l] = v.x; kT[d4*4 + 1][l] = v.y;
        kT[d4*4 + 2][l] = v.z; kT[d4*4 + 3][l] = v.w;
    }
    __syncthreads();

    // Scores: 16*77 = 1232 dot products of length 160
    const float scale = 0.07905694150420949f; // 1/sqrt(160)
    for (int p = t; p < 16 * LTXT; p += 256) {
        const int qi = p / LTXT, l = p % LTXT;
        float dot = 0.f;
#pragma unroll 8
        for (int d = 0; d < HD; ++d) dot += qs[qi][d] * kT[d][l];
        sc[qi][l] = dot * scale;
    }
    __syncthreads();

    // Softmax per query row (16 rows, one thread each)
    if (t < 16) {
        float mx = -1e30f;
        for (int l = 0; l < LTXT; ++l) mx = fmaxf(mx, sc[t][l]);
        float sum = 0.f;
        for (int l = 0; l < LTXT; ++l) { float e = expf(sc[t][l] - mx); sc[t][l] = e; sum += e; }
        const float inv = 1.f / sum;
        for (int l = 0; l < LTXT; ++l) sc[t][l] *= inv;
    }
    __syncthreads();

    // Load V transposed over K's buffer
    const float* vbase = vbuf + ((size_t)(b * LTXT)) * D_MODEL + h * HD;
    for (int idx = t; idx < 3080; idx += 256) {
        const int l = idx / 40, d4 = idx % 40;
        const float4 v = *(const float4*)&vbase[(size_t)l * D_MODEL + d4 * 4];
        kT[d4*4 + 0][l] = v.x; kT[d4*4 + 1][l] = v.y;
        kT[d4*4 + 2][l] = v.z; kT[d4*4 + 3][l] = v.w;
    }
    __syncthreads();

    // hs = probs @ v : 16*160 outputs, each a length-77 reduction
    for (int o = t; o < 16 * HD; o += 256) {
        const int qi = o / HD, d = o % HD;
        float acc = 0.f;
        for (int l = 0; l < LTXT; ++l) acc += sc[qi][l] * kT[d][l];
        qbase[(size_t)qi * D_MODEL + d] = acc;   // in-place over q
    }
}

// ---------------------------------------------------------------------------
extern "C" void kernel_launch(void* const* d_in, const int* in_sizes, int n_in,
                              void* d_out, int out_size, void* d_ws, size_t ws_size,
                              hipStream_t stream)
{
    const float* hidden = (const float*)d_in[0]; // [8,1024,1280]
    const float* enc    = (const float*)d_in[1]; // [8,77,768]
    const float* Wq     = (const float*)d_in[2]; // [1280,1280]
    const float* Wk     = (const float*)d_in[3]; // [768,1280]
    const float* Wv     = (const float*)d_in[4]; // [768,1280]
    const float* Wo     = (const float*)d_in[5]; // [1280,1280]
    const float* bo     = (const float*)d_in[6]; // [1280]
    const float* tv     = (const float*)d_in[7]; // [48,77,160]
    float* out = (float*)d_out;

    float* q    = (float*)d_ws;                         // [8192,1280] (becomes hs in place)
    float* kbuf = q + (size_t)BATCH * S_LEN * D_MODEL;  // [616,1280]
    float* vbuf = kbuf + (size_t)BATCH * LTXT * D_MODEL;

    const int MQ = BATCH * S_LEN;   // 8192
    const int MKV = BATCH * LTXT;   // 616

    // q = hidden @ Wq
    gemm_f32<<<dim3(D_MODEL/64, MQ/64), 256, 0, stream>>>(hidden, Wq, q, MQ, D_MODEL, D_MODEL, nullptr);
    // k = enc @ Wk ; v = enc @ Wv
    gemm_f32<<<dim3(D_MODEL/64, (MKV+63)/64), 256, 0, stream>>>(enc, Wk, kbuf, MKV, DX, D_MODEL, nullptr);
    gemm_f32<<<dim3(D_MODEL/64, (MKV+63)/64), 256, 0, stream>>>(enc, Wv, vbuf, MKV, DX, D_MODEL, nullptr);
    // concept-erasure retain transform on v (in place)
    retain_kernel<<<4 * LTXT, 256, 0, stream>>>(vbuf, tv);
    // attention (hs overwrites q in place)
    attn_kernel<<<dim3(NBH, S_LEN/16), 256, 0, stream>>>(kbuf, vbuf, q);
    // out = hs @ Wo + bo
    gemm_f32<<<dim3(D_MODEL/64, MQ/64), 256, 0, stream>>>(q, Wo, out, MQ, D_MODEL, D_MODEL, bo);
}

// Round 3
// 580.398 us; speedup vs baseline: 1.8935x; 1.8935x over previous
//
#include <hip/hip_runtime.h>
#include <hip/hip_bf16.h>
#include <math.h>

// Problem constants
#define BATCH   8
#define S_LEN   1024
#define D_MODEL 1280
#define DX      768
#define NH      8
#define HD      160
#define LTXT    77
#define NBH     (BATCH*NH)      // 64

typedef __attribute__((ext_vector_type(8))) short bf16x8;
typedef __attribute__((ext_vector_type(4))) float f32x4;

// ---------------------------------------------------------------------------
// split_hilo: X fp32 [M,K] -> Y bf16 [M, 2K]  with Y[m,k]=bf16(X[m,k]),
// Y[m,K+k]=bf16(X[m,k]-float(bf16(X[m,k]))).  Exact-activation decomposition.
// FIX vs round 1: store 4 bf16 through ushort4 (8B), not ushort2 (4B truncation).
// ---------------------------------------------------------------------------
__global__ __launch_bounds__(256) void split_hilo(
    const float* __restrict__ X, __hip_bfloat16* __restrict__ Y, int M, int K)
{
    const size_t g4 = (size_t)blockIdx.x * 256 + threadIdx.x; // group of 4 elems
    const size_t total = (size_t)M * K / 4;
    if (g4 >= total) return;
    const size_t g = g4 * 4;
    const int m = (int)(g / K), k = (int)(g % K);
    const float4 x = *(const float4*)&X[g];
    const float xs[4] = {x.x, x.y, x.z, x.w};
    ushort4 hv, lv;
    unsigned short* hp = &hv.x;
    unsigned short* lp = &lv.x;
#pragma unroll
    for (int j = 0; j < 4; ++j) {
        const __hip_bfloat16 hi = __float2bfloat16(xs[j]);
        const __hip_bfloat16 lo = __float2bfloat16(xs[j] - __bfloat162float(hi));
        hp[j] = *(const unsigned short*)&hi;
        lp[j] = *(const unsigned short*)&lo;
    }
    *(ushort4*)&Y[(size_t)m * 2 * K + k]     = hv;
    *(ushort4*)&Y[(size_t)m * 2 * K + K + k] = lv;
}

// ---------------------------------------------------------------------------
// wt_t_dup: W fp32 [K,N] -> BT bf16 [N, 2K], BT[n,k] = BT[n,K+k] = bf16(W[k,n]).
// LDS-tiled 32x32 transpose. K,N multiples of 32.
// ---------------------------------------------------------------------------
__global__ __launch_bounds__(256) void wt_t_dup(
    const float* __restrict__ W, __hip_bfloat16* __restrict__ BT, int K, int N)
{
    __shared__ float tile[32][33];
    const int k0 = blockIdx.y * 32, n0 = blockIdx.x * 32;
    const int tx = threadIdx.x & 31, ty = threadIdx.x >> 5; // 32 x 8
#pragma unroll
    for (int r = 0; r < 32; r += 8)
        tile[r + ty][tx] = W[(size_t)(k0 + r + ty) * N + n0 + tx];
    __syncthreads();
#pragma unroll
    for (int r = 0; r < 32; r += 8) {
        const int n = n0 + r + ty, k = k0 + tx;
        const __hip_bfloat16 h = __float2bfloat16(tile[tx][r + ty]);
        BT[(size_t)n * 2 * K + k]     = h;
        BT[(size_t)n * 2 * K + K + k] = h;
    }
}

// ---------------------------------------------------------------------------
// MFMA bf16 GEMM, B^T layout:  C[M,N] = A[M,KK] @ B[N,KK]^T (+bias)
// 128x128 tile, BK=32, 4 waves, each wave a 64x64 quadrant (4x4 frags of
// 16x16x32). global_load_lds width-16 staging, linear LDS (m97 structure).
// M%128==0, N%128==0, KK%32==0.
// ---------------------------------------------------------------------------
__device__ inline void async_copy16(const void* gptr, void* lptr) {
    __builtin_amdgcn_global_load_lds(
        (const __attribute__((address_space(1))) unsigned*)gptr,
        (__attribute__((address_space(3))) unsigned*)lptr, 16, 0, 0);
}

__global__ __launch_bounds__(256) void gemm_mfma_bt(
    const __hip_bfloat16* __restrict__ A, const __hip_bfloat16* __restrict__ B,
    float* __restrict__ C, int M, int N, int KK,
    const float* __restrict__ bias)
{
    __shared__ __hip_bfloat16 As[128 * 32];  // [row][k] linear, 8 KB
    __shared__ __hip_bfloat16 Bs[128 * 32];  // [col][k] linear, 8 KB
    const int t = threadIdx.x;
    const int wave = t >> 6, lane = t & 63;
    const int m0 = blockIdx.y * 128, n0 = blockIdx.x * 128;
    const int wr = wave >> 1, wc = wave & 1;

    f32x4 acc[4][4] = {};

    // staging: 8 instrs of 1024B per tile; wave handles instrs {2w, 2w+1}.
    // lane j within instr ti: row = 16*ti + (j>>2), k-offset = (j&3)*8.
    const int srow = lane >> 2;
    const int sk   = (lane & 3) * 8;
    const int ti0 = wave * 2, ti1 = wave * 2 + 1;
    const int ar1 = 16 * ti0 + srow, ar2 = 16 * ti1 + srow;

    for (int k0 = 0; k0 < KK; k0 += 32) {
        __syncthreads();   // previous compute done
        async_copy16(A + (size_t)(m0 + ar1) * KK + k0 + sk, As + ti0 * 512);
        async_copy16(A + (size_t)(m0 + ar2) * KK + k0 + sk, As + ti1 * 512);
        async_copy16(B + (size_t)(n0 + ar1) * KK + k0 + sk, Bs + ti0 * 512);
        async_copy16(B + (size_t)(n0 + ar2) * KK + k0 + sk, Bs + ti1 * 512);
        __syncthreads();   // staging complete (barrier drains vmcnt)

        bf16x8 af[4], bf_[4];
#pragma unroll
        for (int i = 0; i < 4; ++i) {
            af[i]  = *(const bf16x8*)(As + (wr * 64 + i * 16 + (lane & 15)) * 32 + (lane >> 4) * 8);
            bf_[i] = *(const bf16x8*)(Bs + (wc * 64 + i * 16 + (lane & 15)) * 32 + (lane >> 4) * 8);
        }
#pragma unroll
        for (int i = 0; i < 4; ++i)
#pragma unroll
            for (int j = 0; j < 4; ++j)
                acc[i][j] = __builtin_amdgcn_mfma_f32_16x16x32_bf16(af[i], bf_[j], acc[i][j], 0, 0, 0);
    }

    // epilogue: C[row = (lane>>4)*4 + r, col = lane&15] per fragment (m89 layout)
#pragma unroll
    for (int i = 0; i < 4; ++i) {
#pragma unroll
        for (int j = 0; j < 4; ++j) {
            const int col = n0 + wc * 64 + j * 16 + (lane & 15);
            const float bv = bias ? bias[col] : 0.f;
#pragma unroll
            for (int r = 0; r < 4; ++r) {
                const int row = m0 + wr * 64 + i * 16 + (lane >> 4) * 4 + r;
                C[(size_t)row * N + col] = acc[i][j][r] + bv;
            }
        }
    }
}

// ---------------------------------------------------------------------------
// Generic fp32 tiled GEMM (K/V projections + fallback path).
// ---------------------------------------------------------------------------
__global__ __launch_bounds__(256) void gemm_f32(
    const float* __restrict__ A, const float* __restrict__ B,
    float* __restrict__ C, int M, int K, int N,
    const float* __restrict__ bias)
{
    __shared__ float As[16][68];
    __shared__ float Bs[16][68];
    const int t  = threadIdx.x;
    const int tx = t & 15, ty = t >> 4;
    const int m0 = blockIdx.y * 64, n0 = blockIdx.x * 64;
    const int arow = t >> 2, akk = (t & 3) * 4;
    const int brow = t >> 4, bcol = (t & 15) * 4;

    float acc[4][4] = {};

    for (int k0 = 0; k0 < K; k0 += 16) {
        float4 av = make_float4(0.f, 0.f, 0.f, 0.f);
        if (m0 + arow < M)
            av = *(const float4*)&A[(size_t)(m0 + arow) * K + k0 + akk];
        As[akk + 0][arow] = av.x;
        As[akk + 1][arow] = av.y;
        As[akk + 2][arow] = av.z;
        As[akk + 3][arow] = av.w;
        *(float4*)&Bs[brow][bcol] =
            *(const float4*)&B[(size_t)(k0 + brow) * N + n0 + bcol];
        __syncthreads();
#pragma unroll
        for (int kk = 0; kk < 16; ++kk) {
            float a_[4], b_[4];
#pragma unroll
            for (int i = 0; i < 4; ++i) a_[i] = As[kk][ty * 4 + i];
#pragma unroll
            for (int j = 0; j < 4; ++j) b_[j] = Bs[kk][tx * 4 + j];
#pragma unroll
            for (int i = 0; i < 4; ++i)
#pragma unroll
                for (int j = 0; j < 4; ++j) acc[i][j] += a_[i] * b_[j];
        }
        __syncthreads();
    }

#pragma unroll
    for (int i = 0; i < 4; ++i) {
        int row = m0 + ty * 4 + i;
        if (row < M) {
#pragma unroll
            for (int j = 0; j < 4; ++j) {
                int col = n0 + tx * 4 + j;
                float v = acc[i][j];
                if (bias) v += bias[col];
                C[(size_t)row * N + col] = v;
            }
        }
    }
}

// ---------------------------------------------------------------------------
// Ortho-decomp retain transform (unchanged, passing).
// ---------------------------------------------------------------------------
__global__ __launch_bounds__(256) void retain_kernel(
    float* __restrict__ vbuf, const float* __restrict__ tv)
{
    const int l = blockIdx.x % LTXT;
    const int r = blockIdx.x / LTXT;
    const int t = threadIdx.x;

    float g00=0,g01=0,g02=0,g11=0,g12=0,g22=0,tp0=0,tp1=0,tp2=0,pp=0;
    float p_save[10];
#pragma unroll
    for (int it = 0; it < 10; ++it) {
        const int j   = t + it * 256;
        const int m16 = j / HD, d = j % HD;
        const int e = m16 >> 3, h = m16 & 7;
        const float T0 = tv[((size_t)(e*24 +  0 + h) * LTXT + l) * HD + d];
        const float T1 = tv[((size_t)(e*24 +  8 + h) * LTXT + l) * HD + d];
        const float T2 = tv[((size_t)(e*24 + 16 + h) * LTXT + l) * HD + d];
        const float p  = vbuf[((size_t)((e*4 + r) * LTXT + l)) * D_MODEL + h*HD + d];
        p_save[it] = p;
        g00 += T0*T0; g01 += T0*T1; g02 += T0*T2;
        g11 += T1*T1; g12 += T1*T2; g22 += T2*T2;
        tp0 += T0*p;  tp1 += T1*p;  tp2 += T2*p;  pp += p*p;
    }

    __shared__ float part[4][10];
    const int wave = t >> 6, lane = t & 63;
    float vals[10] = {g00,g01,g02,g11,g12,g22,tp0,tp1,tp2,pp};
#pragma unroll
    for (int i = 0; i < 10; ++i) {
        float x = vals[i];
        x += __shfl_down(x, 32); x += __shfl_down(x, 16);
        x += __shfl_down(x,  8); x += __shfl_down(x,  4);
        x += __shfl_down(x,  2); x += __shfl_down(x,  1);
        if (lane == 0) part[wave][i] = x;
    }
    __syncthreads();

    float s[10];
#pragma unroll
    for (int i = 0; i < 10; ++i)
        s[i] = part[0][i] + part[1][i] + part[2][i] + part[3][i];

    const float G[3][3] = {{s[0],s[1],s[2]},{s[1],s[3],s[4]},{s[2],s[4],s[5]}};
    const float tp[3] = {s[6], s[7], s[8]};
    const float ppv = s[9];

    float Pm[3][3];
#pragma unroll
    for (int c = 0; c < 3; ++c)
#pragma unroll
        for (int e = 0; e < 3; ++e) {
            float v = (c == e) ? 1.f : 0.f;
            if (c > e) v -= G[c][e] / G[e][e];
            Pm[c][e] = v;
        }

    const float nP = fmaxf(sqrtf(ppv), 1e-8f);
    float w[3], cosg[3];
#pragma unroll
    for (int c = 0; c < 3; ++c) {
        const float nT = fmaxf(sqrtf(G[c][c]), 1e-8f);
        const float cosv = tp[c] / (nT * nP);
        cosg[c] = 1.f / (1.f + expf(-10.f * (cosv - 0.5f)));
        float d1 = Pm[c][0]*tp[0] + Pm[c][1]*tp[1] + Pm[c][2]*tp[2];
        float d2 = 0.f;
#pragma unroll
        for (int e = 0; e < 3; ++e)
#pragma unroll
            for (int f = 0; f < 3; ++f) d2 += Pm[c][e] * Pm[c][f] * G[e][f];
        float wc = d1 / d2;
        if (isnan(wc)) wc = 0.f;
        if (l == 0)    wc = 0.f;
        w[c] = wc;
    }

    float coef[3];
#pragma unroll
    for (int e = 0; e < 3; ++e)
        coef[e] = cosg[e] * (w[0]*Pm[0][e] + w[1]*Pm[1][e] + w[2]*Pm[2][e]);

#pragma unroll
    for (int it = 0; it < 10; ++it) {
        const int j   = t + it * 256;
        const int m16 = j / HD, d = j % HD;
        const int e = m16 >> 3, h = m16 & 7;
        const float T0 = tv[((size_t)(e*24 +  0 + h) * LTXT + l) * HD + d];
        const float T1 = tv[((size_t)(e*24 +  8 + h) * LTXT + l) * HD + d];
        const float T2 = tv[((size_t)(e*24 + 16 + h) * LTXT + l) * HD + d];
        const float era = coef[0]*T0 + coef[1]*T1 + coef[2]*T2;
        vbuf[((size_t)((e*4 + r) * LTXT + l)) * D_MODEL + h*HD + d] = p_save[it] - era;
    }
}

// ---------------------------------------------------------------------------
// Attention (unchanged, passing).
// ---------------------------------------------------------------------------
__global__ __launch_bounds__(256) void attn_kernel(
    const float* __restrict__ kbuf, const float* __restrict__ vbuf,
    float* __restrict__ qhs)
{
    __shared__ float qs[16][HD];
    __shared__ float kT[HD][78];
    __shared__ float sc[16][78];
    const int bh = blockIdx.x;
    const int b = bh >> 3, h = bh & 7;
    const int q0 = blockIdx.y * 16;
    const int t = threadIdx.x;

    float* qbase = qhs + ((size_t)(b * S_LEN + q0)) * D_MODEL + h * HD;
    for (int idx = t; idx < 640; idx += 256) {
        const int qi = idx / 40, d4 = idx % 40;
        *(float4*)&qs[qi][d4 * 4] = *(const float4*)&qbase[(size_t)qi * D_MODEL + d4 * 4];
    }
    const float* kbase = kbuf + ((size_t)(b * LTXT)) * D_MODEL + h * HD;
    for (int idx = t; idx < 3080; idx += 256) {
        const int l = idx / 40, d4 = idx % 40;
        const float4 v = *(const float4*)&kbase[(size_t)l * D_MODEL + d4 * 4];
        kT[d4*4 + 0][l] = v.x; kT[d4*4 + 1][l] = v.y;
        kT[d4*4 + 2][l] = v.z; kT[d4*4 + 3][l] = v.w;
    }
    __syncthreads();

    const float scale = 0.07905694150420949f;
    for (int p = t; p < 16 * LTXT; p += 256) {
        const int qi = p / LTXT, l = p % LTXT;
        float dot = 0.f;
#pragma unroll 8
        for (int d = 0; d < HD; ++d) dot += qs[qi][d] * kT[d][l];
        sc[qi][l] = dot * scale;
    }
    __syncthreads();

    if (t < 16) {
        float mx = -1e30f;
        for (int l = 0; l < LTXT; ++l) mx = fmaxf(mx, sc[t][l]);
        float sum = 0.f;
        for (int l = 0; l < LTXT; ++l) { float e = expf(sc[t][l] - mx); sc[t][l] = e; sum += e; }
        const float inv = 1.f / sum;
        for (int l = 0; l < LTXT; ++l) sc[t][l] *= inv;
    }
    __syncthreads();

    const float* vbase = vbuf + ((size_t)(b * LTXT)) * D_MODEL + h * HD;
    for (int idx = t; idx < 3080; idx += 256) {
        const int l = idx / 40, d4 = idx % 40;
        const float4 v = *(const float4*)&vbase[(size_t)l * D_MODEL + d4 * 4];
        kT[d4*4 + 0][l] = v.x; kT[d4*4 + 1][l] = v.y;
        kT[d4*4 + 2][l] = v.z; kT[d4*4 + 3][l] = v.w;
    }
    __syncthreads();

    for (int o = t; o < 16 * HD; o += 256) {
        const int qi = o / HD, d = o % HD;
        float acc = 0.f;
        for (int l = 0; l < LTXT; ++l) acc += sc[qi][l] * kT[d][l];
        qbase[(size_t)qi * D_MODEL + d] = acc;
    }
}

// ---------------------------------------------------------------------------
extern "C" void kernel_launch(void* const* d_in, const int* in_sizes, int n_in,
                              void* d_out, int out_size, void* d_ws, size_t ws_size,
                              hipStream_t stream)
{
    const float* hidden = (const float*)d_in[0]; // [8,1024,1280]
    const float* enc    = (const float*)d_in[1]; // [8,77,768]
    const float* Wq     = (const float*)d_in[2]; // [1280,1280]
    const float* Wk     = (const float*)d_in[3]; // [768,1280]
    const float* Wv     = (const float*)d_in[4]; // [768,1280]
    const float* Wo     = (const float*)d_in[5]; // [1280,1280]
    const float* bo     = (const float*)d_in[6]; // [1280]
    const float* tv     = (const float*)d_in[7]; // [48,77,160]
    float* out = (float*)d_out;

    const int MQ  = BATCH * S_LEN;  // 8192
    const int MKV = BATCH * LTXT;   // 616
    const int KK  = 2 * D_MODEL;    // 2560 (hi|lo split K)

    float* q    = (float*)d_ws;                           // [8192,1280] fp32 (becomes hs)
    float* kbuf = q + (size_t)MQ * D_MODEL;
    float* vbuf = kbuf + (size_t)MKV * D_MODEL;
    __hip_bfloat16* A2  = (__hip_bfloat16*)(vbuf + (size_t)MKV * D_MODEL); // [8192, 2560]
    __hip_bfloat16* B2T = A2 + (size_t)MQ * KK;                            // [1280, 2560]

    const size_t ws_needed = ((size_t)MQ + 2 * (size_t)MKV) * D_MODEL * sizeof(float)
                           + ((size_t)MQ + (size_t)D_MODEL) * KK * sizeof(__hip_bfloat16);
    const bool use_mfma = (ws_size >= ws_needed);

    // ---- Q = hidden @ Wq ----
    if (use_mfma) {
        split_hilo<<<(MQ * D_MODEL / 4 + 255) / 256, 256, 0, stream>>>(hidden, A2, MQ, D_MODEL);
        wt_t_dup<<<dim3(D_MODEL / 32, D_MODEL / 32), 256, 0, stream>>>(Wq, B2T, D_MODEL, D_MODEL);
        gemm_mfma_bt<<<dim3(D_MODEL / 128, MQ / 128), 256, 0, stream>>>(A2, B2T, q, MQ, D_MODEL, KK, nullptr);
    } else {
        gemm_f32<<<dim3(D_MODEL/64, MQ/64), 256, 0, stream>>>(hidden, Wq, q, MQ, D_MODEL, D_MODEL, nullptr);
    }

    // ---- K, V projections (small, fp32) ----
    gemm_f32<<<dim3(D_MODEL/64, (MKV+63)/64), 256, 0, stream>>>(enc, Wk, kbuf, MKV, DX, D_MODEL, nullptr);
    gemm_f32<<<dim3(D_MODEL/64, (MKV+63)/64), 256, 0, stream>>>(enc, Wv, vbuf, MKV, DX, D_MODEL, nullptr);

    // ---- concept-erasure retain transform on v (in place) ----
    retain_kernel<<<4 * LTXT, 256, 0, stream>>>(vbuf, tv);

    // ---- attention (hs overwrites q in place) ----
    attn_kernel<<<dim3(NBH, S_LEN/16), 256, 0, stream>>>(kbuf, vbuf, q);

    // ---- out = hs @ Wo + bo ----
    if (use_mfma) {
        split_hilo<<<(MQ * D_MODEL / 4 + 255) / 256, 256, 0, stream>>>(q, A2, MQ, D_MODEL);
        wt_t_dup<<<dim3(D_MODEL / 32, D_MODEL / 32), 256, 0, stream>>>(Wo, B2T, D_MODEL, D_MODEL);
        gemm_mfma_bt<<<dim3(D_MODEL / 128, MQ / 128), 256, 0, stream>>>(A2, B2T, out, MQ, D_MODEL, KK, bo);
    } else {
        gemm_f32<<<dim3(D_MODEL/64, MQ/64), 256, 0, stream>>>(q, Wo, out, MQ, D_MODEL, D_MODEL, bo);
    }
}

// Round 4
// 347.919 us; speedup vs baseline: 3.1587x; 1.6682x over previous
//
#include <hip/hip_runtime.h>
#include <hip/hip_bf16.h>
#include <math.h>

// Problem constants
#define BATCH   8
#define S_LEN   1024
#define D_MODEL 1280
#define DX      768
#define NH      8
#define HD      160
#define LTXT    77
#define NBH     (BATCH*NH)      // 64

typedef __attribute__((ext_vector_type(8))) short bf16x8;
typedef __attribute__((ext_vector_type(4))) float f32x4;

// ---------------------------------------------------------------------------
// split_hilo: X fp32 [M,K] -> Y bf16 [M, 2K]  (exact-activation decomposition)
// ---------------------------------------------------------------------------
__global__ __launch_bounds__(256) void split_hilo(
    const float* __restrict__ X, __hip_bfloat16* __restrict__ Y, int M, int K)
{
    const size_t g4 = (size_t)blockIdx.x * 256 + threadIdx.x;
    const size_t total = (size_t)M * K / 4;
    if (g4 >= total) return;
    const size_t g = g4 * 4;
    const int m = (int)(g / K), k = (int)(g % K);
    const float4 x = *(const float4*)&X[g];
    const float xs[4] = {x.x, x.y, x.z, x.w};
    ushort4 hv, lv;
    unsigned short* hp = &hv.x;
    unsigned short* lp = &lv.x;
#pragma unroll
    for (int j = 0; j < 4; ++j) {
        const __hip_bfloat16 hi = __float2bfloat16(xs[j]);
        const __hip_bfloat16 lo = __float2bfloat16(xs[j] - __bfloat162float(hi));
        hp[j] = *(const unsigned short*)&hi;
        lp[j] = *(const unsigned short*)&lo;
    }
    *(ushort4*)&Y[(size_t)m * 2 * K + k]     = hv;
    *(ushort4*)&Y[(size_t)m * 2 * K + K + k] = lv;
}

// ---------------------------------------------------------------------------
// wt_t_dup: W fp32 [K,N] -> BT bf16 [N, 2K], BT[n,k] = BT[n,K+k] = bf16(W[k,n]).
// ---------------------------------------------------------------------------
__global__ __launch_bounds__(256) void wt_t_dup(
    const float* __restrict__ W, __hip_bfloat16* __restrict__ BT, int K, int N)
{
    __shared__ float tile[32][33];
    const int k0 = blockIdx.y * 32, n0 = blockIdx.x * 32;
    const int tx = threadIdx.x & 31, ty = threadIdx.x >> 5;
#pragma unroll
    for (int r = 0; r < 32; r += 8)
        tile[r + ty][tx] = W[(size_t)(k0 + r + ty) * N + n0 + tx];
    __syncthreads();
#pragma unroll
    for (int r = 0; r < 32; r += 8) {
        const int n = n0 + r + ty, k = k0 + tx;
        const __hip_bfloat16 h = __float2bfloat16(tile[tx][r + ty]);
        BT[(size_t)n * 2 * K + k]     = h;
        BT[(size_t)n * 2 * K + K + k] = h;
    }
}

// ---------------------------------------------------------------------------
// MFMA bf16 GEMM, B^T layout:  C[M,N] = A[M,KK] @ B[N,KK]^T (+bias)
// Output fp32 (Cf) or bf16 (Cb) depending on which pointer is non-null.
// ---------------------------------------------------------------------------
__device__ inline void async_copy16(const void* gptr, void* lptr) {
    __builtin_amdgcn_global_load_lds(
        (const __attribute__((address_space(1))) unsigned*)gptr,
        (__attribute__((address_space(3))) unsigned*)lptr, 16, 0, 0);
}

__global__ __launch_bounds__(256) void gemm_mfma_bt(
    const __hip_bfloat16* __restrict__ A, const __hip_bfloat16* __restrict__ B,
    float* __restrict__ Cf, __hip_bfloat16* __restrict__ Cb,
    int M, int N, int KK, const float* __restrict__ bias)
{
    __shared__ __hip_bfloat16 As[128 * 32];
    __shared__ __hip_bfloat16 Bs[128 * 32];
    const int t = threadIdx.x;
    const int wave = t >> 6, lane = t & 63;
    const int m0 = blockIdx.y * 128, n0 = blockIdx.x * 128;
    const int wr = wave >> 1, wc = wave & 1;

    f32x4 acc[4][4] = {};

    const int srow = lane >> 2;
    const int sk   = (lane & 3) * 8;
    const int ti0 = wave * 2, ti1 = wave * 2 + 1;
    const int ar1 = 16 * ti0 + srow, ar2 = 16 * ti1 + srow;

    for (int k0 = 0; k0 < KK; k0 += 32) {
        __syncthreads();
        async_copy16(A + (size_t)(m0 + ar1) * KK + k0 + sk, As + ti0 * 512);
        async_copy16(A + (size_t)(m0 + ar2) * KK + k0 + sk, As + ti1 * 512);
        async_copy16(B + (size_t)(n0 + ar1) * KK + k0 + sk, Bs + ti0 * 512);
        async_copy16(B + (size_t)(n0 + ar2) * KK + k0 + sk, Bs + ti1 * 512);
        __syncthreads();

        bf16x8 af[4], bf_[4];
#pragma unroll
        for (int i = 0; i < 4; ++i) {
            af[i]  = *(const bf16x8*)(As + (wr * 64 + i * 16 + (lane & 15)) * 32 + (lane >> 4) * 8);
            bf_[i] = *(const bf16x8*)(Bs + (wc * 64 + i * 16 + (lane & 15)) * 32 + (lane >> 4) * 8);
        }
#pragma unroll
        for (int i = 0; i < 4; ++i)
#pragma unroll
            for (int j = 0; j < 4; ++j)
                acc[i][j] = __builtin_amdgcn_mfma_f32_16x16x32_bf16(af[i], bf_[j], acc[i][j], 0, 0, 0);
    }

#pragma unroll
    for (int i = 0; i < 4; ++i) {
#pragma unroll
        for (int j = 0; j < 4; ++j) {
            const int col = n0 + wc * 64 + j * 16 + (lane & 15);
            const float bv = bias ? bias[col] : 0.f;
#pragma unroll
            for (int r = 0; r < 4; ++r) {
                const int row = m0 + wr * 64 + i * 16 + (lane >> 4) * 4 + r;
                const float v = acc[i][j][r] + bv;
                if (Cb) Cb[(size_t)row * N + col] = __float2bfloat16(v);
                else    Cf[(size_t)row * N + col] = v;
            }
        }
    }
}

// ---------------------------------------------------------------------------
// Generic fp32 tiled GEMM (K/V projections).
// ---------------------------------------------------------------------------
__global__ __launch_bounds__(256) void gemm_f32(
    const float* __restrict__ A, const float* __restrict__ B,
    float* __restrict__ C, int M, int K, int N,
    const float* __restrict__ bias)
{
    __shared__ float As[16][68];
    __shared__ float Bs[16][68];
    const int t  = threadIdx.x;
    const int tx = t & 15, ty = t >> 4;
    const int m0 = blockIdx.y * 64, n0 = blockIdx.x * 64;
    const int arow = t >> 2, akk = (t & 3) * 4;
    const int brow = t >> 4, bcol = (t & 15) * 4;

    float acc[4][4] = {};

    for (int k0 = 0; k0 < K; k0 += 16) {
        float4 av = make_float4(0.f, 0.f, 0.f, 0.f);
        if (m0 + arow < M)
            av = *(const float4*)&A[(size_t)(m0 + arow) * K + k0 + akk];
        As[akk + 0][arow] = av.x;
        As[akk + 1][arow] = av.y;
        As[akk + 2][arow] = av.z;
        As[akk + 3][arow] = av.w;
        *(float4*)&Bs[brow][bcol] =
            *(const float4*)&B[(size_t)(k0 + brow) * N + n0 + bcol];
        __syncthreads();
#pragma unroll
        for (int kk = 0; kk < 16; ++kk) {
            float a_[4], b_[4];
#pragma unroll
            for (int i = 0; i < 4; ++i) a_[i] = As[kk][ty * 4 + i];
#pragma unroll
            for (int j = 0; j < 4; ++j) b_[j] = Bs[kk][tx * 4 + j];
#pragma unroll
            for (int i = 0; i < 4; ++i)
#pragma unroll
                for (int j = 0; j < 4; ++j) acc[i][j] += a_[i] * b_[j];
        }
        __syncthreads();
    }

#pragma unroll
    for (int i = 0; i < 4; ++i) {
        int row = m0 + ty * 4 + i;
        if (row < M) {
#pragma unroll
            for (int j = 0; j < 4; ++j) {
                int col = n0 + tx * 4 + j;
                float v = acc[i][j];
                if (bias) v += bias[col];
                C[(size_t)row * N + col] = v;
            }
        }
    }
}

// ---------------------------------------------------------------------------
// Ortho-decomp retain transform (unchanged, passing).
// ---------------------------------------------------------------------------
__global__ __launch_bounds__(256) void retain_kernel(
    float* __restrict__ vbuf, const float* __restrict__ tv)
{
    const int l = blockIdx.x % LTXT;
    const int r = blockIdx.x / LTXT;
    const int t = threadIdx.x;

    float g00=0,g01=0,g02=0,g11=0,g12=0,g22=0,tp0=0,tp1=0,tp2=0,pp=0;
    float p_save[10];
#pragma unroll
    for (int it = 0; it < 10; ++it) {
        const int j   = t + it * 256;
        const int m16 = j / HD, d = j % HD;
        const int e = m16 >> 3, h = m16 & 7;
        const float T0 = tv[((size_t)(e*24 +  0 + h) * LTXT + l) * HD + d];
        const float T1 = tv[((size_t)(e*24 +  8 + h) * LTXT + l) * HD + d];
        const float T2 = tv[((size_t)(e*24 + 16 + h) * LTXT + l) * HD + d];
        const float p  = vbuf[((size_t)((e*4 + r) * LTXT + l)) * D_MODEL + h*HD + d];
        p_save[it] = p;
        g00 += T0*T0; g01 += T0*T1; g02 += T0*T2;
        g11 += T1*T1; g12 += T1*T2; g22 += T2*T2;
        tp0 += T0*p;  tp1 += T1*p;  tp2 += T2*p;  pp += p*p;
    }

    __shared__ float part[4][10];
    const int wave = t >> 6, lane = t & 63;
    float vals[10] = {g00,g01,g02,g11,g12,g22,tp0,tp1,tp2,pp};
#pragma unroll
    for (int i = 0; i < 10; ++i) {
        float x = vals[i];
        x += __shfl_down(x, 32); x += __shfl_down(x, 16);
        x += __shfl_down(x,  8); x += __shfl_down(x,  4);
        x += __shfl_down(x,  2); x += __shfl_down(x,  1);
        if (lane == 0) part[wave][i] = x;
    }
    __syncthreads();

    float s[10];
#pragma unroll
    for (int i = 0; i < 10; ++i)
        s[i] = part[0][i] + part[1][i] + part[2][i] + part[3][i];

    const float G[3][3] = {{s[0],s[1],s[2]},{s[1],s[3],s[4]},{s[2],s[4],s[5]}};
    const float tp[3] = {s[6], s[7], s[8]};
    const float ppv = s[9];

    float Pm[3][3];
#pragma unroll
    for (int c = 0; c < 3; ++c)
#pragma unroll
        for (int e = 0; e < 3; ++e) {
            float v = (c == e) ? 1.f : 0.f;
            if (c > e) v -= G[c][e] / G[e][e];
            Pm[c][e] = v;
        }

    const float nP = fmaxf(sqrtf(ppv), 1e-8f);
    float w[3], cosg[3];
#pragma unroll
    for (int c = 0; c < 3; ++c) {
        const float nT = fmaxf(sqrtf(G[c][c]), 1e-8f);
        const float cosv = tp[c] / (nT * nP);
        cosg[c] = 1.f / (1.f + expf(-10.f * (cosv - 0.5f)));
        float d1 = Pm[c][0]*tp[0] + Pm[c][1]*tp[1] + Pm[c][2]*tp[2];
        float d2 = 0.f;
#pragma unroll
        for (int e = 0; e < 3; ++e)
#pragma unroll
            for (int f = 0; f < 3; ++f) d2 += Pm[c][e] * Pm[c][f] * G[e][f];
        float wc = d1 / d2;
        if (isnan(wc)) wc = 0.f;
        if (l == 0)    wc = 0.f;
        w[c] = wc;
    }

    float coef[3];
#pragma unroll
    for (int e = 0; e < 3; ++e)
        coef[e] = cosg[e] * (w[0]*Pm[0][e] + w[1]*Pm[1][e] + w[2]*Pm[2][e]);

#pragma unroll
    for (int it = 0; it < 10; ++it) {
        const int j   = t + it * 256;
        const int m16 = j / HD, d = j % HD;
        const int e = m16 >> 3, h = m16 & 7;
        const float T0 = tv[((size_t)(e*24 +  0 + h) * LTXT + l) * HD + d];
        const float T1 = tv[((size_t)(e*24 +  8 + h) * LTXT + l) * HD + d];
        const float T2 = tv[((size_t)(e*24 + 16 + h) * LTXT + l) * HD + d];
        const float era = coef[0]*T0 + coef[1]*T1 + coef[2]*T2;
        vbuf[((size_t)((e*4 + r) * LTXT + l)) * D_MODEL + h*HD + d] = p_save[it] - era;
    }
}

// ---------------------------------------------------------------------------
// MFMA attention. Block = (b,h) x 64 queries (4 waves x 16 rows each).
// QK^T and PV via mfma_f32_16x16x32_bf16; in-register wave-parallel softmax;
// epilogue writes hs directly as hi/lo split into A2 (out-GEMM A operand).
// LDS: KV union (K view [80][168] / V^T view [160][104]) + per-wave P tiles.
// Strides chosen so 16-lane frag reads are 2-way bank aliased (free, m136).
// ---------------------------------------------------------------------------
#define KSTRIDE 168
#define VSTRIDE 104
#define PSTRIDE 104

__global__ __launch_bounds__(256, 3) void attn_mfma(
    const __hip_bfloat16* __restrict__ qb,   // [8192][1280] bf16
    const float* __restrict__ kbuf,          // [616][1280] fp32
    const float* __restrict__ vbuf,          // [616][1280] fp32 (retained)
    __hip_bfloat16* __restrict__ A2)         // [8192][2560] hi/lo out
{
    __shared__ __hip_bfloat16 KV[160 * VSTRIDE];    // 33280 B (K view: [80][KSTRIDE])
    __shared__ __hip_bfloat16 Ps[4][16 * PSTRIDE];  // 13312 B
    const int bh = blockIdx.x, b = bh >> 3, h = bh & 7;
    const int qt = blockIdx.y;
    const int t = threadIdx.x, wave = t >> 6, lane = t & 63;
    const int lr = lane & 15, lg = lane >> 4;

    // ---- stage K as [80][KSTRIDE] bf16, rows >=77 zeroed
    for (int c = t; c < 3200; c += 256) {
        const int l = c / 40, d4 = (c % 40) * 4;
        float4 kv = make_float4(0.f, 0.f, 0.f, 0.f);
        if (l < LTXT) kv = *(const float4*)&kbuf[((size_t)(b * LTXT + l)) * D_MODEL + h * HD + d4];
        const __hip_bfloat16 b0 = __float2bfloat16(kv.x), b1 = __float2bfloat16(kv.y),
                             b2 = __float2bfloat16(kv.z), b3 = __float2bfloat16(kv.w);
        ushort4 u;
        u.x = *(const unsigned short*)&b0; u.y = *(const unsigned short*)&b1;
        u.z = *(const unsigned short*)&b2; u.w = *(const unsigned short*)&b3;
        *(ushort4*)&KV[l * KSTRIDE + d4] = u;
    }
    // zero own wave's P pad cols 80..95 (PV k-dim padded to 96)
    {
        const __hip_bfloat16 z = __float2bfloat16(0.f);
        for (int i = lane; i < 256; i += 64)
            Ps[wave][(i >> 4) * PSTRIDE + 80 + (i & 15)] = z;
    }
    __syncthreads();

    // ---- Q fragments direct from global bf16
    const int qrow0 = b * S_LEN + qt * 64 + wave * 16;
    const __hip_bfloat16* qp = qb + (size_t)(qrow0 + lr) * D_MODEL + h * HD;
    bf16x8 af[5];
#pragma unroll
    for (int kt = 0; kt < 5; ++kt)
        af[kt] = *(const bf16x8*)&qp[kt * 32 + lg * 8];

    // ---- QK^T: 5 key-tiles x 5 k-tiles
    f32x4 accs[5] = {};
#pragma unroll
    for (int j = 0; j < 5; ++j)
#pragma unroll
        for (int kt = 0; kt < 5; ++kt) {
            const bf16x8 bf = *(const bf16x8*)&KV[(j * 16 + lr) * KSTRIDE + kt * 32 + lg * 8];
            accs[j] = __builtin_amdgcn_mfma_f32_16x16x32_bf16(af[kt], bf, accs[j], 0, 0, 0);
        }

    // ---- softmax: row = lg*4 + r lives in this 16-lane group
    float s[5][4];
    const float scale = 0.07905694150420949f; // 1/sqrt(160)
#pragma unroll
    for (int j = 0; j < 5; ++j)
#pragma unroll
        for (int r = 0; r < 4; ++r)
            s[j][r] = accs[j][r] * scale;
    if (lr >= 13) { s[4][0] = -1e30f; s[4][1] = -1e30f; s[4][2] = -1e30f; s[4][3] = -1e30f; }

    float rsum[4];
#pragma unroll
    for (int r = 0; r < 4; ++r) {
        float m = s[0][r];
#pragma unroll
        for (int j = 1; j < 5; ++j) m = fmaxf(m, s[j][r]);
        m = fmaxf(m, __shfl_xor(m, 1));
        m = fmaxf(m, __shfl_xor(m, 2));
        m = fmaxf(m, __shfl_xor(m, 4));
        m = fmaxf(m, __shfl_xor(m, 8));
        float sum = 0.f;
#pragma unroll
        for (int j = 0; j < 5; ++j) {
            const float p = __expf(s[j][r] - m);
            s[j][r] = p;
            sum += p;
        }
        sum += __shfl_xor(sum, 1);
        sum += __shfl_xor(sum, 2);
        sum += __shfl_xor(sum, 4);
        sum += __shfl_xor(sum, 8);
        rsum[r] = sum;
    }

    // ---- store P (unnormalized) to own wave's LDS tile
#pragma unroll
    for (int j = 0; j < 5; ++j)
#pragma unroll
        for (int r = 0; r < 4; ++r)
            Ps[wave][(lg * 4 + r) * PSTRIDE + j * 16 + lr] = __float2bfloat16(s[j][r]);

    __syncthreads();   // all waves done reading K view of KV

    // ---- stage V^T as [160][VSTRIDE] bf16, key cols >=77 zeroed (pad to 96)
    for (int c = t; c < 3840; c += 256) {
        const int l = c / 40, d4 = (c % 40) * 4;
        float4 vv = make_float4(0.f, 0.f, 0.f, 0.f);
        if (l < LTXT) vv = *(const float4*)&vbuf[((size_t)(b * LTXT + l)) * D_MODEL + h * HD + d4];
        KV[(d4 + 0) * VSTRIDE + l] = __float2bfloat16(vv.x);
        KV[(d4 + 1) * VSTRIDE + l] = __float2bfloat16(vv.y);
        KV[(d4 + 2) * VSTRIDE + l] = __float2bfloat16(vv.z);
        KV[(d4 + 3) * VSTRIDE + l] = __float2bfloat16(vv.w);
    }
    __syncthreads();

    // ---- PV: hs[16 x 160] = P[16 x 96] @ V[96 x 160]
    bf16x8 pa[3];
#pragma unroll
    for (int kt = 0; kt < 3; ++kt)
        pa[kt] = *(const bf16x8*)&Ps[wave][lr * PSTRIDE + kt * 32 + lg * 8];
    f32x4 acch[10] = {};
#pragma unroll
    for (int dt = 0; dt < 10; ++dt)
#pragma unroll
        for (int kt = 0; kt < 3; ++kt) {
            const bf16x8 vb = *(const bf16x8*)&KV[(dt * 16 + lr) * VSTRIDE + kt * 32 + lg * 8];
            acch[dt] = __builtin_amdgcn_mfma_f32_16x16x32_bf16(pa[kt], vb, acch[dt], 0, 0, 0);
        }

    // ---- epilogue: normalize (deferred softmax div), hi/lo split into A2
    const float inv[4] = {1.f / rsum[0], 1.f / rsum[1], 1.f / rsum[2], 1.f / rsum[3]};
#pragma unroll
    for (int dt = 0; dt < 10; ++dt) {
        const int col = h * HD + dt * 16 + lr;
#pragma unroll
        for (int r = 0; r < 4; ++r) {
            const int row = qrow0 + lg * 4 + r;
            const float x = acch[dt][r] * inv[r];
            const __hip_bfloat16 hi = __float2bfloat16(x);
            const __hip_bfloat16 lo = __float2bfloat16(x - __bfloat162float(hi));
            A2[(size_t)row * (2 * D_MODEL) + col] = hi;
            A2[(size_t)row * (2 * D_MODEL) + D_MODEL + col] = lo;
        }
    }
}

// ---------------------------------------------------------------------------
extern "C" void kernel_launch(void* const* d_in, const int* in_sizes, int n_in,
                              void* d_out, int out_size, void* d_ws, size_t ws_size,
                              hipStream_t stream)
{
    const float* hidden = (const float*)d_in[0]; // [8,1024,1280]
    const float* enc    = (const float*)d_in[1]; // [8,77,768]
    const float* Wq     = (const float*)d_in[2]; // [1280,1280]
    const float* Wk     = (const float*)d_in[3]; // [768,1280]
    const float* Wv     = (const float*)d_in[4]; // [768,1280]
    const float* Wo     = (const float*)d_in[5]; // [1280,1280]
    const float* bo     = (const float*)d_in[6]; // [1280]
    const float* tv     = (const float*)d_in[7]; // [48,77,160]
    float* out = (float*)d_out;

    const int MQ  = BATCH * S_LEN;  // 8192
    const int MKV = BATCH * LTXT;   // 616
    const int KK  = 2 * D_MODEL;    // 2560

    // ws layout (offsets unchanged vs round 2; q region now holds bf16 q in its
    // first half): q | kbuf | vbuf | A2 | B2T
    float* qreg = (float*)d_ws;                           // [8192,1280] region
    float* kbuf = qreg + (size_t)MQ * D_MODEL;
    float* vbuf = kbuf + (size_t)MKV * D_MODEL;
    __hip_bfloat16* A2  = (__hip_bfloat16*)(vbuf + (size_t)MKV * D_MODEL); // [8192, 2560]
    __hip_bfloat16* B2T = A2 + (size_t)MQ * KK;                            // [1280, 2560]
    __hip_bfloat16* qbf = (__hip_bfloat16*)qreg;                           // [8192, 1280] bf16

    // ---- Q = bf16(hidden @ Wq) via exact-activation split MFMA ----
    split_hilo<<<(MQ * D_MODEL / 4 + 255) / 256, 256, 0, stream>>>(hidden, A2, MQ, D_MODEL);
    wt_t_dup<<<dim3(D_MODEL / 32, D_MODEL / 32), 256, 0, stream>>>(Wq, B2T, D_MODEL, D_MODEL);
    gemm_mfma_bt<<<dim3(D_MODEL / 128, MQ / 128), 256, 0, stream>>>(A2, B2T, nullptr, qbf, MQ, D_MODEL, KK, nullptr);

    // ---- K, V projections (fp32) ----
    gemm_f32<<<dim3(D_MODEL/64, (MKV+63)/64), 256, 0, stream>>>(enc, Wk, kbuf, MKV, DX, D_MODEL, nullptr);
    gemm_f32<<<dim3(D_MODEL/64, (MKV+63)/64), 256, 0, stream>>>(enc, Wv, vbuf, MKV, DX, D_MODEL, nullptr);

    // ---- concept-erasure retain transform on v (in place, fp32) ----
    retain_kernel<<<4 * LTXT, 256, 0, stream>>>(vbuf, tv);

    // ---- MFMA attention: writes hs as hi/lo split directly into A2 ----
    attn_mfma<<<dim3(NBH, S_LEN / 64), 256, 0, stream>>>(qbf, kbuf, vbuf, A2);

    // ---- out = hs @ Wo + bo ----
    wt_t_dup<<<dim3(D_MODEL / 32, D_MODEL / 32), 256, 0, stream>>>(Wo, B2T, D_MODEL, D_MODEL);
    gemm_mfma_bt<<<dim3(D_MODEL / 128, MQ / 128), 256, 0, stream>>>(A2, B2T, out, nullptr, MQ, D_MODEL, KK, bo);
}

// Round 5
// 248.039 us; speedup vs baseline: 4.4307x; 1.4027x over previous
//
#include <hip/hip_runtime.h>
#include <hip/hip_bf16.h>
#include <math.h>

// Problem constants
#define BATCH   8
#define S_LEN   1024
#define D_MODEL 1280
#define DX      768
#define NH      8
#define HD      160
#define LTXT    77
#define NBH     (BATCH*NH)      // 64
#define MKV_PAD 640             // 616 padded to 128-multiple

typedef __attribute__((ext_vector_type(8))) short bf16x8;
typedef __attribute__((ext_vector_type(4))) float f32x4;

// ---------------------------------------------------------------------------
// split_hilo: X fp32 [M,K] -> Y bf16 [M, 2K]  (exact-activation decomposition)
// ---------------------------------------------------------------------------
__global__ __launch_bounds__(256) void split_hilo(
    const float* __restrict__ X, __hip_bfloat16* __restrict__ Y, int M, int K)
{
    const size_t g4 = (size_t)blockIdx.x * 256 + threadIdx.x;
    const size_t total = (size_t)M * K / 4;
    if (g4 >= total) return;
    const size_t g = g4 * 4;
    const int m = (int)(g / K), k = (int)(g % K);
    const float4 x = *(const float4*)&X[g];
    const float xs[4] = {x.x, x.y, x.z, x.w};
    ushort4 hv, lv;
    unsigned short* hp = &hv.x;
    unsigned short* lp = &lv.x;
#pragma unroll
    for (int j = 0; j < 4; ++j) {
        const __hip_bfloat16 hi = __float2bfloat16(xs[j]);
        const __hip_bfloat16 lo = __float2bfloat16(xs[j] - __bfloat162float(hi));
        hp[j] = *(const unsigned short*)&hi;
        lp[j] = *(const unsigned short*)&lo;
    }
    *(ushort4*)&Y[(size_t)m * 2 * K + k]     = hv;
    *(ushort4*)&Y[(size_t)m * 2 * K + K + k] = lv;
}

// ---------------------------------------------------------------------------
// wt_t_dup: W fp32 [K,N] -> BT bf16 [N, 2K], BT[n,k] = BT[n,K+k] = bf16(W[k,n]).
// ---------------------------------------------------------------------------
__global__ __launch_bounds__(256) void wt_t_dup(
    const float* __restrict__ W, __hip_bfloat16* __restrict__ BT, int K, int N)
{
    __shared__ float tile[32][33];
    const int k0 = blockIdx.y * 32, n0 = blockIdx.x * 32;
    const int tx = threadIdx.x & 31, ty = threadIdx.x >> 5;
#pragma unroll
    for (int r = 0; r < 32; r += 8)
        tile[r + ty][tx] = W[(size_t)(k0 + r + ty) * N + n0 + tx];
    __syncthreads();
#pragma unroll
    for (int r = 0; r < 32; r += 8) {
        const int n = n0 + r + ty, k = k0 + tx;
        const __hip_bfloat16 h = __float2bfloat16(tile[tx][r + ty]);
        BT[(size_t)n * 2 * K + k]     = h;
        BT[(size_t)n * 2 * K + K + k] = h;
    }
}

// ---------------------------------------------------------------------------
// wt_t: W fp32 [K,N] -> BT bf16 rows [noff+n][k] (row stride KLD), no dup.
// Used to build the fused [Wk|Wv]^T operand: BT[2560][768].
// ---------------------------------------------------------------------------
__global__ __launch_bounds__(256) void wt_t(
    const float* __restrict__ W, __hip_bfloat16* __restrict__ BT,
    int K, int N, int KLD, int noff)
{
    __shared__ float tile[32][33];
    const int k0 = blockIdx.y * 32, n0 = blockIdx.x * 32;
    const int tx = threadIdx.x & 31, ty = threadIdx.x >> 5;
#pragma unroll
    for (int r = 0; r < 32; r += 8)
        tile[r + ty][tx] = W[(size_t)(k0 + r + ty) * N + n0 + tx];
    __syncthreads();
#pragma unroll
    for (int r = 0; r < 32; r += 8) {
        const int n = noff + n0 + r + ty, k = k0 + tx;
        BT[(size_t)n * KLD + k] = __float2bfloat16(tile[tx][r + ty]);
    }
}

// ---------------------------------------------------------------------------
// enc_to_bf16: enc fp32 [616,768] -> encb bf16 [640,768], rows 616..639 zero.
// ---------------------------------------------------------------------------
__global__ __launch_bounds__(256) void enc_to_bf16(
    const float* __restrict__ enc, __hip_bfloat16* __restrict__ encb)
{
    const int g4 = blockIdx.x * 256 + threadIdx.x;
    if (g4 >= MKV_PAD * DX / 4) return;
    const int row = g4 / (DX / 4), c4 = (g4 % (DX / 4)) * 4;
    float4 v = make_float4(0.f, 0.f, 0.f, 0.f);
    if (row < BATCH * LTXT) v = *(const float4*)&enc[(size_t)row * DX + c4];
    const float xs[4] = {v.x, v.y, v.z, v.w};
    ushort4 u;
    unsigned short* up = &u.x;
#pragma unroll
    for (int j = 0; j < 4; ++j) {
        const __hip_bfloat16 h = __float2bfloat16(xs[j]);
        up[j] = *(const unsigned short*)&h;
    }
    *(ushort4*)&encb[(size_t)row * DX + c4] = u;
}

// ---------------------------------------------------------------------------
// MFMA bf16 GEMM, B^T layout: C[M,N] = A[M,KK] @ B[N,KK]^T (+bias)
// 128x128 tile, BK=64, 4 waves (64x64 quadrant each, 4x4 frags of 16x16x32).
// T2 XOR-swizzled LDS via pre-swizzled global source (linear gload_lds dest,
// kelem = 8*((lane&7)^(lane>>3))) + same XOR on ds_read (rule #21).
// T1 bijective XCD-chunk swizzle on a 1-D grid (m204 formula).
// Output modes: kout!=0 -> split fp32 store into kout/vout (col<1280 / >=1280,
// rows guarded by Mreal); else Cb!=0 -> bf16; else Cf fp32.
// ---------------------------------------------------------------------------
__device__ inline void async_copy16(const void* gptr, void* lptr) {
    __builtin_amdgcn_global_load_lds(
        (const __attribute__((address_space(1))) unsigned*)gptr,
        (__attribute__((address_space(3))) unsigned*)lptr, 16, 0, 0);
}

__global__ __launch_bounds__(256) void gemm_mfma_bt(
    const __hip_bfloat16* __restrict__ A, const __hip_bfloat16* __restrict__ B,
    float* __restrict__ Cf, __hip_bfloat16* __restrict__ Cb,
    float* __restrict__ kout, float* __restrict__ vout,
    int Mreal, int N, int KK, int ntn, const float* __restrict__ bias)
{
    __shared__ __align__(16) __hip_bfloat16 As[128 * 64];  // 16 KB
    __shared__ __align__(16) __hip_bfloat16 Bs[128 * 64];  // 16 KB
    const int t = threadIdx.x;
    const int wave = t >> 6, lane = t & 63;
    const int lr = lane & 15, lg = lane >> 4;
    const int wr = wave >> 1, wc = wave & 1;

    // T1 bijective XCD-chunk swizzle (m204)
    const int nwg = gridDim.x;
    const int q = nwg >> 3, r = nwg & 7;
    const int xcd = blockIdx.x & 7, idx = blockIdx.x >> 3;
    const int swz = (xcd < r ? xcd * (q + 1) : r * (q + 1) + (xcd - r) * q) + idx;
    const int m0 = (swz / ntn) * 128, n0 = (swz % ntn) * 128;

    f32x4 acc[4][4] = {};

    // staging: per K-step 16 KB/matrix = 16 instrs of 1KB; wave does 4+4.
    // instr ti: 8 rows (lane>>3), 16B chunk (lane&7); source k pre-swizzled.
    const int sr = lane >> 3;                   // row within instr
    const int sk = 8 * ((lane & 7) ^ sr);       // swizzled k-elem offset

    for (int k0 = 0; k0 < KK; k0 += 64) {
        __syncthreads();   // previous compute done
#pragma unroll
        for (int s = 0; s < 4; ++s) {
            const int ti = wave * 4 + s;
            const int row = ti * 8 + sr;
            async_copy16(A + (size_t)(m0 + row) * KK + k0 + sk, As + ti * 512);
            async_copy16(B + (size_t)(n0 + row) * KK + k0 + sk, Bs + ti * 512);
        }
        __syncthreads();   // staging complete (barrier drains vmcnt)

        bf16x8 af[4][2], bf_[4][2];
#pragma unroll
        for (int i = 0; i < 4; ++i)
#pragma unroll
            for (int ki = 0; ki < 2; ++ki) {
                const int koff = (ki * 32 + lg * 8) ^ ((lr & 7) * 8);
                af[i][ki]  = *(const bf16x8*)(As + (wr * 64 + i * 16 + lr) * 64 + koff);
                bf_[i][ki] = *(const bf16x8*)(Bs + (wc * 64 + i * 16 + lr) * 64 + koff);
            }
#pragma unroll
        for (int ki = 0; ki < 2; ++ki)
#pragma unroll
            for (int i = 0; i < 4; ++i)
#pragma unroll
                for (int j = 0; j < 4; ++j)
                    acc[i][j] = __builtin_amdgcn_mfma_f32_16x16x32_bf16(
                        af[i][ki], bf_[j][ki], acc[i][j], 0, 0, 0);
    }

    // epilogue: C row = lg*4 + rr, col = lr within fragment (m89 layout)
#pragma unroll
    for (int i = 0; i < 4; ++i) {
#pragma unroll
        for (int j = 0; j < 4; ++j) {
            const int col = n0 + wc * 64 + j * 16 + lr;
            const float bv = bias ? bias[col] : 0.f;
#pragma unroll
            for (int rr = 0; rr < 4; ++rr) {
                const int row = m0 + wr * 64 + i * 16 + lg * 4 + rr;
                const float v = acc[i][j][rr] + bv;
                if (kout) {
                    if (row < Mreal) {
                        if (col < D_MODEL) kout[(size_t)row * D_MODEL + col] = v;
                        else               vout[(size_t)row * D_MODEL + col - D_MODEL] = v;
                    }
                } else if (Cb) {
                    Cb[(size_t)row * N + col] = __float2bfloat16(v);
                } else {
                    Cf[(size_t)row * N + col] = v;
                }
            }
        }
    }
}

// ---------------------------------------------------------------------------
// Ortho-decomp retain transform (T cached in registers across both passes).
// ---------------------------------------------------------------------------
__global__ __launch_bounds__(256) void retain_kernel(
    float* __restrict__ vbuf, const float* __restrict__ tv)
{
    const int l = blockIdx.x % LTXT;
    const int r = blockIdx.x / LTXT;
    const int t = threadIdx.x;

    float g00=0,g01=0,g02=0,g11=0,g12=0,g22=0,tp0=0,tp1=0,tp2=0,pp=0;
    float p_save[10], t0s[10], t1s[10], t2s[10];
#pragma unroll
    for (int it = 0; it < 10; ++it) {
        const int j   = t + it * 256;
        const int m16 = j / HD, d = j % HD;
        const int e = m16 >> 3, h = m16 & 7;
        const float T0 = tv[((size_t)(e*24 +  0 + h) * LTXT + l) * HD + d];
        const float T1 = tv[((size_t)(e*24 +  8 + h) * LTXT + l) * HD + d];
        const float T2 = tv[((size_t)(e*24 + 16 + h) * LTXT + l) * HD + d];
        const float p  = vbuf[((size_t)((e*4 + r) * LTXT + l)) * D_MODEL + h*HD + d];
        p_save[it] = p; t0s[it] = T0; t1s[it] = T1; t2s[it] = T2;
        g00 += T0*T0; g01 += T0*T1; g02 += T0*T2;
        g11 += T1*T1; g12 += T1*T2; g22 += T2*T2;
        tp0 += T0*p;  tp1 += T1*p;  tp2 += T2*p;  pp += p*p;
    }

    __shared__ float part[4][10];
    const int wave = t >> 6, lane = t & 63;
    float vals[10] = {g00,g01,g02,g11,g12,g22,tp0,tp1,tp2,pp};
#pragma unroll
    for (int i = 0; i < 10; ++i) {
        float x = vals[i];
        x += __shfl_down(x, 32); x += __shfl_down(x, 16);
        x += __shfl_down(x,  8); x += __shfl_down(x,  4);
        x += __shfl_down(x,  2); x += __shfl_down(x,  1);
        if (lane == 0) part[wave][i] = x;
    }
    __syncthreads();

    float s[10];
#pragma unroll
    for (int i = 0; i < 10; ++i)
        s[i] = part[0][i] + part[1][i] + part[2][i] + part[3][i];

    const float G[3][3] = {{s[0],s[1],s[2]},{s[1],s[3],s[4]},{s[2],s[4],s[5]}};
    const float tp[3] = {s[6], s[7], s[8]};
    const float ppv = s[9];

    float Pm[3][3];
#pragma unroll
    for (int c = 0; c < 3; ++c)
#pragma unroll
        for (int e = 0; e < 3; ++e) {
            float v = (c == e) ? 1.f : 0.f;
            if (c > e) v -= G[c][e] / G[e][e];
            Pm[c][e] = v;
        }

    const float nP = fmaxf(sqrtf(ppv), 1e-8f);
    float w[3], cosg[3];
#pragma unroll
    for (int c = 0; c < 3; ++c) {
        const float nT = fmaxf(sqrtf(G[c][c]), 1e-8f);
        const float cosv = tp[c] / (nT * nP);
        cosg[c] = 1.f / (1.f + expf(-10.f * (cosv - 0.5f)));
        float d1 = Pm[c][0]*tp[0] + Pm[c][1]*tp[1] + Pm[c][2]*tp[2];
        float d2 = 0.f;
#pragma unroll
        for (int e = 0; e < 3; ++e)
#pragma unroll
            for (int f = 0; f < 3; ++f) d2 += Pm[c][e] * Pm[c][f] * G[e][f];
        float wc = d1 / d2;
        if (isnan(wc)) wc = 0.f;
        if (l == 0)    wc = 0.f;
        w[c] = wc;
    }

    float coef[3];
#pragma unroll
    for (int e = 0; e < 3; ++e)
        coef[e] = cosg[e] * (w[0]*Pm[0][e] + w[1]*Pm[1][e] + w[2]*Pm[2][e]);

#pragma unroll
    for (int it = 0; it < 10; ++it) {
        const int j   = t + it * 256;
        const int m16 = j / HD, d = j % HD;
        const int e = m16 >> 3, h = m16 & 7;
        const float era = coef[0]*t0s[it] + coef[1]*t1s[it] + coef[2]*t2s[it];
        vbuf[((size_t)((e*4 + r) * LTXT + l)) * D_MODEL + h*HD + d] = p_save[it] - era;
    }
}

// ---------------------------------------------------------------------------
// MFMA attention (unchanged from round 3, passing).
// ---------------------------------------------------------------------------
#define KSTRIDE 168
#define VSTRIDE 104
#define PSTRIDE 104

__global__ __launch_bounds__(256, 3) void attn_mfma(
    const __hip_bfloat16* __restrict__ qb,
    const float* __restrict__ kbuf,
    const float* __restrict__ vbuf,
    __hip_bfloat16* __restrict__ A2)
{
    __shared__ __hip_bfloat16 KV[160 * VSTRIDE];
    __shared__ __hip_bfloat16 Ps[4][16 * PSTRIDE];
    const int bh = blockIdx.x, b = bh >> 3, h = bh & 7;
    const int qt = blockIdx.y;
    const int t = threadIdx.x, wave = t >> 6, lane = t & 63;
    const int lr = lane & 15, lg = lane >> 4;

    for (int c = t; c < 3200; c += 256) {
        const int l = c / 40, d4 = (c % 40) * 4;
        float4 kv = make_float4(0.f, 0.f, 0.f, 0.f);
        if (l < LTXT) kv = *(const float4*)&kbuf[((size_t)(b * LTXT + l)) * D_MODEL + h * HD + d4];
        const __hip_bfloat16 b0 = __float2bfloat16(kv.x), b1 = __float2bfloat16(kv.y),
                             b2 = __float2bfloat16(kv.z), b3 = __float2bfloat16(kv.w);
        ushort4 u;
        u.x = *(const unsigned short*)&b0; u.y = *(const unsigned short*)&b1;
        u.z = *(const unsigned short*)&b2; u.w = *(const unsigned short*)&b3;
        *(ushort4*)&KV[l * KSTRIDE + d4] = u;
    }
    {
        const __hip_bfloat16 z = __float2bfloat16(0.f);
        for (int i = lane; i < 256; i += 64)
            Ps[wave][(i >> 4) * PSTRIDE + 80 + (i & 15)] = z;
    }
    __syncthreads();

    const int qrow0 = b * S_LEN + qt * 64 + wave * 16;
    const __hip_bfloat16* qp = qb + (size_t)(qrow0 + lr) * D_MODEL + h * HD;
    bf16x8 af[5];
#pragma unroll
    for (int kt = 0; kt < 5; ++kt)
        af[kt] = *(const bf16x8*)&qp[kt * 32 + lg * 8];

    f32x4 accs[5] = {};
#pragma unroll
    for (int j = 0; j < 5; ++j)
#pragma unroll
        for (int kt = 0; kt < 5; ++kt) {
            const bf16x8 bf = *(const bf16x8*)&KV[(j * 16 + lr) * KSTRIDE + kt * 32 + lg * 8];
            accs[j] = __builtin_amdgcn_mfma_f32_16x16x32_bf16(af[kt], bf, accs[j], 0, 0, 0);
        }

    float s[5][4];
    const float scale = 0.07905694150420949f;
#pragma unroll
    for (int j = 0; j < 5; ++j)
#pragma unroll
        for (int r = 0; r < 4; ++r)
            s[j][r] = accs[j][r] * scale;
    if (lr >= 13) { s[4][0] = -1e30f; s[4][1] = -1e30f; s[4][2] = -1e30f; s[4][3] = -1e30f; }

    float rsum[4];
#pragma unroll
    for (int r = 0; r < 4; ++r) {
        float m = s[0][r];
#pragma unroll
        for (int j = 1; j < 5; ++j) m = fmaxf(m, s[j][r]);
        m = fmaxf(m, __shfl_xor(m, 1));
        m = fmaxf(m, __shfl_xor(m, 2));
        m = fmaxf(m, __shfl_xor(m, 4));
        m = fmaxf(m, __shfl_xor(m, 8));
        float sum = 0.f;
#pragma unroll
        for (int j = 0; j < 5; ++j) {
            const float p = __expf(s[j][r] - m);
            s[j][r] = p;
            sum += p;
        }
        sum += __shfl_xor(sum, 1);
        sum += __shfl_xor(sum, 2);
        sum += __shfl_xor(sum, 4);
        sum += __shfl_xor(sum, 8);
        rsum[r] = sum;
    }

#pragma unroll
    for (int j = 0; j < 5; ++j)
#pragma unroll
        for (int r = 0; r < 4; ++r)
            Ps[wave][(lg * 4 + r) * PSTRIDE + j * 16 + lr] = __float2bfloat16(s[j][r]);

    __syncthreads();

    for (int c = t; c < 3840; c += 256) {
        const int l = c / 40, d4 = (c % 40) * 4;
        float4 vv = make_float4(0.f, 0.f, 0.f, 0.f);
        if (l < LTXT) vv = *(const float4*)&vbuf[((size_t)(b * LTXT + l)) * D_MODEL + h * HD + d4];
        KV[(d4 + 0) * VSTRIDE + l] = __float2bfloat16(vv.x);
        KV[(d4 + 1) * VSTRIDE + l] = __float2bfloat16(vv.y);
        KV[(d4 + 2) * VSTRIDE + l] = __float2bfloat16(vv.z);
        KV[(d4 + 3) * VSTRIDE + l] = __float2bfloat16(vv.w);
    }
    __syncthreads();

    bf16x8 pa[3];
#pragma unroll
    for (int kt = 0; kt < 3; ++kt)
        pa[kt] = *(const bf16x8*)&Ps[wave][lr * PSTRIDE + kt * 32 + lg * 8];
    f32x4 acch[10] = {};
#pragma unroll
    for (int dt = 0; dt < 10; ++dt)
#pragma unroll
        for (int kt = 0; kt < 3; ++kt) {
            const bf16x8 vb = *(const bf16x8*)&KV[(dt * 16 + lr) * VSTRIDE + kt * 32 + lg * 8];
            acch[dt] = __builtin_amdgcn_mfma_f32_16x16x32_bf16(pa[kt], vb, acch[dt], 0, 0, 0);
        }

    const float inv[4] = {1.f / rsum[0], 1.f / rsum[1], 1.f / rsum[2], 1.f / rsum[3]};
#pragma unroll
    for (int dt = 0; dt < 10; ++dt) {
        const int col = h * HD + dt * 16 + lr;
#pragma unroll
        for (int r = 0; r < 4; ++r) {
            const int row = qrow0 + lg * 4 + r;
            const float x = acch[dt][r] * inv[r];
            const __hip_bfloat16 hi = __float2bfloat16(x);
            const __hip_bfloat16 lo = __float2bfloat16(x - __bfloat162float(hi));
            A2[(size_t)row * (2 * D_MODEL) + col] = hi;
            A2[(size_t)row * (2 * D_MODEL) + D_MODEL + col] = lo;
        }
    }
}

// ---------------------------------------------------------------------------
extern "C" void kernel_launch(void* const* d_in, const int* in_sizes, int n_in,
                              void* d_out, int out_size, void* d_ws, size_t ws_size,
                              hipStream_t stream)
{
    const float* hidden = (const float*)d_in[0]; // [8,1024,1280]
    const float* enc    = (const float*)d_in[1]; // [8,77,768]
    const float* Wq     = (const float*)d_in[2]; // [1280,1280]
    const float* Wk     = (const float*)d_in[3]; // [768,1280]
    const float* Wv     = (const float*)d_in[4]; // [768,1280]
    const float* Wo     = (const float*)d_in[5]; // [1280,1280]
    const float* bo     = (const float*)d_in[6]; // [1280]
    const float* tv     = (const float*)d_in[7]; // [48,77,160]
    float* out = (float*)d_out;

    const int MQ  = BATCH * S_LEN;  // 8192
    const int MKV = BATCH * LTXT;   // 616
    const int KK  = 2 * D_MODEL;    // 2560

    // ws layout: qreg [8192*1280 f32 region] | kbuf | vbuf | A2 | B2T
    float* qreg = (float*)d_ws;
    float* kbuf = qreg + (size_t)MQ * D_MODEL;
    float* vbuf = kbuf + (size_t)MKV * D_MODEL;
    __hip_bfloat16* A2  = (__hip_bfloat16*)(vbuf + (size_t)MKV * D_MODEL); // [8192,2560]
    __hip_bfloat16* B2T = A2 + (size_t)MQ * KK;                            // [1280,2560]
    __hip_bfloat16* qbf = (__hip_bfloat16*)qreg;                           // [8192,1280] bf16 (first half of qreg)
    __hip_bfloat16* encb = qbf + (size_t)MQ * D_MODEL;                     // [640,768] bf16 (second half of qreg)
    __hip_bfloat16* B2Tkv = B2T;                                           // [2560,768] bf16 (reuses B2T region)

    // ---- Q = bf16(hidden @ Wq), exact-activation split MFMA ----
    split_hilo<<<(MQ * D_MODEL / 4 + 255) / 256, 256, 0, stream>>>(hidden, A2, MQ, D_MODEL);
    wt_t_dup<<<dim3(D_MODEL / 32, D_MODEL / 32), 256, 0, stream>>>(Wq, B2T, D_MODEL, D_MODEL);
    gemm_mfma_bt<<<(MQ / 128) * (D_MODEL / 128), 256, 0, stream>>>(
        A2, B2T, nullptr, qbf, nullptr, nullptr, MQ, D_MODEL, KK, D_MODEL / 128, nullptr);

    // ---- fused K|V projection: [640,768]bf16 @ [2560,768]^T -> kbuf,vbuf ----
    enc_to_bf16<<<(MKV_PAD * DX / 4 + 255) / 256, 256, 0, stream>>>(enc, encb);
    wt_t<<<dim3(D_MODEL / 32, DX / 32), 256, 0, stream>>>(Wk, B2Tkv, DX, D_MODEL, DX, 0);
    wt_t<<<dim3(D_MODEL / 32, DX / 32), 256, 0, stream>>>(Wv, B2Tkv, DX, D_MODEL, DX, D_MODEL);
    gemm_mfma_bt<<<(MKV_PAD / 128) * (2 * D_MODEL / 128), 256, 0, stream>>>(
        encb, B2Tkv, nullptr, nullptr, kbuf, vbuf, MKV, 2 * D_MODEL, DX, 2 * D_MODEL / 128, nullptr);

    // ---- concept-erasure retain transform on v (in place, fp32) ----
    retain_kernel<<<4 * LTXT, 256, 0, stream>>>(vbuf, tv);

    // ---- MFMA attention: writes hs as hi/lo split directly into A2 ----
    attn_mfma<<<dim3(NBH, S_LEN / 64), 256, 0, stream>>>(qbf, kbuf, vbuf, A2);

    // ---- out = hs @ Wo + bo ----
    wt_t_dup<<<dim3(D_MODEL / 32, D_MODEL / 32), 256, 0, stream>>>(Wo, B2T, D_MODEL, D_MODEL);
    gemm_mfma_bt<<<(MQ / 128) * (D_MODEL / 128), 256, 0, stream>>>(
        A2, B2T, out, nullptr, nullptr, nullptr, MQ, D_MODEL, KK, D_MODEL / 128, bo);
}